// Round 13
// baseline (70.258 us; speedup 1.0000x reference)
//
#include <hip/hip_runtime.h>

#define LEAKY_S 0.01f
#define BN_EPS 1e-5f
#define LOG2E 1.44269504088896340736f

typedef float f32x2 __attribute__((ext_vector_type(2)));
typedef float f32x4 __attribute__((ext_vector_type(4)));

__device__ __forceinline__ float leaky(float v) { return v >= 0.0f ? v : LEAKY_S * v; }
__device__ __forceinline__ float fast_exp2(float v) { return __builtin_amdgcn_exp2f(v); }
// sigmoid(z) with weights pre-scaled by log2e
__device__ __forceinline__ float sig2(float z2) {
    return __builtin_amdgcn_rcpf(1.0f + fast_exp2(-z2));
}
__device__ __forceinline__ void st4(float* p, float a, float b, float c, float d) {
    f32x4 v = {a, b, c, d}; *(f32x4*)p = v;   // cached store (R7 winner)
}

// Wave0 helper: fold BN1 + Linear2 into coef[0..15]=a[j], coef[16]=c0.
__device__ __forceinline__ void fold_bn1(const float* __restrict__ p1,
        const float* __restrict__ w2, const float* __restrict__ b2,
        const float* __restrict__ g1, const float* __restrict__ be1,
        float* coef, int tid, float invB) {
    float acc = 0.f;
    for (int i = 0; i < 64; ++i) acc += p1[i * 32 + tid];
    float qacc = __shfl(acc, tid + 16, 64);   // lanes 0..15 fetch sumsq
    float cp = 0.f;
    if (tid < 16) {
        float mean = acc * invB;
        float var  = qacc * invB - mean * mean;
        float inv  = rsqrtf(var + BN_EPS) * g1[tid];
        float sh   = fmaf(-mean, inv, be1[tid]);
        coef[tid] = inv * w2[tid];
        cp = sh * w2[tid];
    }
    for (int off = 8; off >= 1; off >>= 1) cp += __shfl_xor(cp, off, 16);
    if (tid == 0) coef[16] = cp + b2[0];
}

// ---- K1+K2 fused. Device barrier via arrival counter that is RESET TO 0 by
// ---- an async memset node at the head of every launch/replay (graph-legal,
// ---- deterministic). 64 blocks on 256 CUs: co-residency unconditional.
__global__ __launch_bounds__(256) void k_stats(const float* __restrict__ x,
        const float* __restrict__ w1, const float* __restrict__ b1,
        const float* __restrict__ w2, const float* __restrict__ b2,
        const float* __restrict__ g1, const float* __restrict__ be1,
        float* __restrict__ p1, float* __restrict__ p2,
        float* __restrict__ cfws, unsigned int* __restrict__ ctr,
        int B, float invB) {
    int tid = threadIdx.x;
    float w1r[16], b1r[16];
#pragma unroll
    for (int j = 0; j < 16; ++j) { w1r[j] = w1[j]; b1r[j] = b1[j]; }
    int i = blockIdx.x * 256 + tid;
    f32x2 xv = {0.f, 0.f};
    bool have = (2 * i < B);
    if (have) xv = *(const f32x2*)(x + 2 * i);

    // ---- Phase A: BN1 partials ----
    {
        float s[16], q[16];
#pragma unroll
        for (int j = 0; j < 16; ++j) { s[j] = 0.f; q[j] = 0.f; }
        if (have) {
#pragma unroll
            for (int e = 0; e < 2; ++e) {
#pragma unroll
                for (int j = 0; j < 16; ++j) {
                    float h = leaky(fmaf(xv[e], w1r[j], b1r[j]));
                    s[j] += h; q[j] += h * h;
                }
            }
        }
#pragma unroll
        for (int j = 0; j < 16; ++j) {
            for (int off = 32; off >= 1; off >>= 1) {
                s[j] += __shfl_xor(s[j], off, 64);
                q[j] += __shfl_xor(q[j], off, 64);
            }
        }
        __shared__ float red[4][32];
        int w = tid >> 6, lane = tid & 63;
        if (lane == 0) {
#pragma unroll
            for (int j = 0; j < 16; ++j) { red[w][j] = s[j]; red[w][j + 16] = q[j]; }
        }
        __syncthreads();
        if (tid < 32)
            p1[blockIdx.x * 32 + tid] = red[0][tid] + red[1][tid] + red[2][tid] + red[3][tid];
    }

    // ---- Device-scope arrival barrier (ctr reset to 0 each launch) ----
    __threadfence();                       // p1 visible before arrival
    if (tid == 0) {
        atomicAdd(ctr, 1u);
        while (atomicAdd(ctr, 0u) < 64u) { __builtin_amdgcn_s_sleep(1); }
    }
    __syncthreads();
    __threadfence();                       // others' p1 writes now visible

    // ---- Phase B: fold BN1 (each block), publish coef (block 0), h2 partials
    __shared__ float coef[17];
    if (tid < 32) fold_bn1(p1, w2, b2, g1, be1, coef, tid, invB);
    __syncthreads();
    if (blockIdx.x == 0 && tid < 17) cfws[tid] = coef[tid];
    float ar[16];
#pragma unroll
    for (int j = 0; j < 16; ++j) ar[j] = coef[j];
    float c0 = coef[16];
    float s = 0.f, q = 0.f;
    if (have) {
#pragma unroll
        for (int e = 0; e < 2; ++e) {
            float acc = c0;
#pragma unroll
            for (int j = 0; j < 16; ++j) {
                float h = leaky(fmaf(xv[e], w1r[j], b1r[j]));
                acc = fmaf(h, ar[j], acc);
            }
            float h2 = leaky(acc);
            s += h2; q += h2 * h2;
        }
    }
    for (int off = 32; off >= 1; off >>= 1) {
        s += __shfl_xor(s, off, 64);
        q += __shfl_xor(q, off, 64);
    }
    __shared__ float red2[4][2];
    int w = tid >> 6, lane = tid & 63;
    if (lane == 0) { red2[w][0] = s; red2[w][1] = q; }
    __syncthreads();
    if (tid == 0) {
        p2[blockIdx.x * 2 + 0] = red2[0][0] + red2[1][0] + red2[2][0] + red2[3][0];
        p2[blockIdx.x * 2 + 1] = red2[0][1] + red2[1][1] + red2[2][1] + red2[3][1];
    }
}

// ---------------- K3: register tree (R11, unchanged) ------------------------
__global__ __launch_bounds__(256, 4) void k_tree(const float* __restrict__ x,
        const float* __restrict__ w1, const float* __restrict__ b1,
        const float* __restrict__ g2, const float* __restrict__ be2,
        const float* __restrict__ fcw, const float* __restrict__ fcb,
        const float* __restrict__ p2, const float* __restrict__ cfws,
        float* __restrict__ out, int B, float invB, int iters, int nw) {
    __shared__ float wl[1024], bl[1024];
    __shared__ float x2s[64];      // h2 per (it, wave) pair, idx = it*4 + w
    __shared__ float bn2[2];       // s2, t2
    int tid = threadIdx.x;

    // Stage fc weights raw, swizzled slot-major (same map as R3).
    for (int i = tid; i < 1024; i += 256) {
        int d;
        if (i < 128)      d = i;
        else if (i < 256) { int o = i - 128; d = 128 + ((o & 1) << 6) + (o >> 1); }
        else if (i < 512) { int o = i - 256; d = 256 + ((((o >> 7) << 1) | (o & 1)) << 6) + ((o & 127) >> 1); }
        else              { int o = i - 512; d = 512 + ((((o >> 7) << 1) | (o & 1)) << 6) + ((o & 127) >> 1); }
        wl[d] = fcw[i];
        bl[d] = fcb[i];
    }
    // Wave0: parallel BN2 stats reduce (64 partial pairs)
    if (tid < 64) {
        float s = p2[2 * tid], q = p2[2 * tid + 1];
        for (int off = 32; off >= 1; off >>= 1) {
            s += __shfl_xor(s, off, 64);
            q += __shfl_xor(q, off, 64);
        }
        if (tid == 0) {
            float mean = s * invB, var = q * invB - mean * mean;
            float inv = rsqrtf(var + BN_EPS) * g2[0];
            bn2[0] = inv;
            bn2[1] = fmaf(-mean, inv, be2[0]);
        }
    }
    // Wave1: h2 for this block's row set {blockIdx*4 + (rr&3) + (rr>>2)*nw}
    if (tid >= 64 && tid < 128) {
        int rr = tid - 64;
        if (rr < 4 * iters) {
            int r = blockIdx.x * 4 + (rr & 3) + (rr >> 2) * nw;
            float xv = (r < B) ? x[r] : 0.f;
            float acc = cfws[16];
#pragma unroll
            for (int j = 0; j < 16; ++j) {
                float h = leaky(fmaf(xv, w1[j], b1[j]));
                acc = fmaf(h, cfws[j], acc);
            }
            x2s[rr] = leaky(acc);
        }
    }
    __syncthreads();
    // Fold BN2 into weights: z*log2e = h2*(s2*w*log2e) + (t2*w + b)*log2e
    {
        float s2k = bn2[0] * LOG2E, t2 = bn2[1];
        for (int i = tid; i < 1024; i += 256) {
            float wv = wl[i];
            wl[i] = wv * s2k;
            bl[i] = fmaf(t2, wv, bl[i]) * LOG2E;
        }
    }
    __syncthreads();

    const int w = tid >> 6, lane = tid & 63;
#pragma unroll 1
    for (int it = 0; it < iters; ++it) {
        const int r = blockIdx.x * 4 + w + it * nw;
        const bool act = r < B;              // wave-uniform
        const float x2 = x2s[it * 4 + w];
        float* op = out + (size_t)r * 2048;

        float s0q[4];                        // segment 0: floats 4*lane .. +3
        float mup;
        // ---- level 1 (uniform across lanes; no shuffle needed) ----
        {
            float z = fmaf(x2, wl[1], bl[1]);
            float pz = sig2(z);
            float c0 = pz, c1 = 1.0f - pz;   // mu parent = 1
            if (lane == 0) { s0q[0] = 0.f; s0q[1] = 1.f; s0q[2] = c0; s0q[3] = c1; }
            mup = (lane & 1) ? c1 : c0;
        }
        // ---- levels 2..6: shuffle levels; gather children into seg0 ----
#pragma unroll
        for (int l = 2; l <= 6; ++l) {
            const int P = 1 << (l - 1);
            float wv = wl[P + lane], bv = bl[P + lane];
            float z = fmaf(x2, wv, bv);
            float pz = sig2(z);
            float c0 = mup * pz, c1 = mup - c0;     // valid in lanes < P
            int sk = (2 * lane - P) & 63;
            float g0 = __shfl(c0, sk, 64);
            float g1 = __shfl(c1, sk, 64);
            float g2 = __shfl(c0, sk + 1, 64);
            float g3 = __shfl(c1, sk + 1, 64);
            if (lane >= P / 2 && lane < P) { s0q[0] = g0; s0q[1] = g1; s0q[2] = g2; s0q[3] = g3; }
            float n0 = __shfl(c0, lane >> 1, 64);
            float n1 = __shfl(c1, lane >> 1, 64);
            mup = (lane & 1) ? n1 : n0;
        }
        // ---- level 7: parent 64+lane; children stay in-lane + gather seg0 ----
        float c2v[2];
        {
            float wv = wl[64 + lane], bv = bl[64 + lane];
            float z = fmaf(x2, wv, bv);
            float pz = sig2(z);
            c2v[0] = mup * pz;
            c2v[1] = mup - c2v[0];
            int sk = (2 * lane - 64) & 63;
            float g0 = __shfl(c2v[0], sk, 64);
            float g1 = __shfl(c2v[1], sk, 64);
            float g2 = __shfl(c2v[0], sk + 1, 64);
            float g3 = __shfl(c2v[1], sk + 1, 64);
            if (lane >= 32) { s0q[0] = g0; s0q[1] = g1; s0q[2] = g2; s0q[3] = g3; }
        }
        // ---- level 8: parents {128+2i, 128+2i+1}; mus in-lane (c2v) ----
        float c4v[4];
#pragma unroll
        for (int s = 0; s < 2; ++s) {
            float wv = wl[128 + (s << 6) + lane], bv = bl[128 + (s << 6) + lane];
            float z = fmaf(x2, wv, bv);
            float pz = sig2(z);
            c4v[2 * s]     = c2v[s] * pz;
            c4v[2 * s + 1] = c2v[s] - c4v[2 * s];
        }
        // ---- level 9: parents {256 + j2*128 + 2i + s} ----
        float c8v[2][4];
#pragma unroll
        for (int j2 = 0; j2 < 2; ++j2) {
            int src = (j2 << 5) + (lane >> 1);
            float A  = __shfl(c4v[0], src, 64);
            float Bv = __shfl(c4v[1], src, 64);
            float C  = __shfl(c4v[2], src, 64);
            float D  = __shfl(c4v[3], src, 64);
            float m0 = (lane & 1) ? C : A;
            float m1 = (lane & 1) ? D : Bv;
            float wv0 = wl[256 + ((2 * j2) << 6) + lane],     bv0 = bl[256 + ((2 * j2) << 6) + lane];
            float wv1 = wl[256 + ((2 * j2 + 1) << 6) + lane], bv1 = bl[256 + ((2 * j2 + 1) << 6) + lane];
            float z0 = fmaf(x2, wv0, bv0);
            float z1 = fmaf(x2, wv1, bv1);
            float p0 = sig2(z0), p1v = sig2(z1);
            c8v[j2][0] = m0 * p0;
            c8v[j2][1] = m0 - c8v[j2][0];
            c8v[j2][2] = m1 * p1v;
            c8v[j2][3] = m1 - c8v[j2][2];
        }
        // ---- level 10: parents {512 + j*128 + 2i + s} ----
        float l10[4][4];
#pragma unroll
        for (int j = 0; j < 4; ++j) {
            const int j2 = j >> 1;
            int src = ((j & 1) << 5) + (lane >> 1);
            float A  = __shfl(c8v[j2][0], src, 64);
            float Bv = __shfl(c8v[j2][1], src, 64);
            float C  = __shfl(c8v[j2][2], src, 64);
            float D  = __shfl(c8v[j2][3], src, 64);
            float m0 = (lane & 1) ? C : A;
            float m1 = (lane & 1) ? D : Bv;
            float wv0 = wl[512 + ((2 * j) << 6) + lane],     bv0 = bl[512 + ((2 * j) << 6) + lane];
            float wv1 = wl[512 + ((2 * j + 1) << 6) + lane], bv1 = bl[512 + ((2 * j + 1) << 6) + lane];
            float z0 = fmaf(x2, wv0, bv0);
            float z1 = fmaf(x2, wv1, bv1);
            float p0 = sig2(z0), p1v = sig2(z1);
            l10[j][0] = m0 * p0;
            l10[j][1] = m0 - l10[j][0];
            l10[j][2] = m1 * p1v;
            l10[j][3] = m1 - l10[j][2];
        }
        // ---- burst: 8 back-to-back lane-contiguous dwordx4 cached stores ----
        if (act) {
            const int o4 = lane << 2;
            st4(op + o4,        s0q[0],    s0q[1],    s0q[2],    s0q[3]);
            st4(op + 256 + o4,  c4v[0],    c4v[1],    c4v[2],    c4v[3]);
            st4(op + 512 + o4,  c8v[0][0], c8v[0][1], c8v[0][2], c8v[0][3]);
            st4(op + 768 + o4,  c8v[1][0], c8v[1][1], c8v[1][2], c8v[1][3]);
            st4(op + 1024 + o4, l10[0][0], l10[0][1], l10[0][2], l10[0][3]);
            st4(op + 1280 + o4, l10[1][0], l10[1][1], l10[1][2], l10[1][3]);
            st4(op + 1536 + o4, l10[2][0], l10[2][1], l10[2][2], l10[2][3]);
            st4(op + 1792 + o4, l10[3][0], l10[3][1], l10[3][2], l10[3][3]);
        }
    }
}

extern "C" void kernel_launch(void* const* d_in, const int* in_sizes, int n_in,
                              void* d_out, int out_size, void* d_ws, size_t ws_size,
                              hipStream_t stream) {
    const float* x   = (const float*)d_in[0];
    const float* w1  = (const float*)d_in[1];
    const float* b1  = (const float*)d_in[2];
    const float* g1  = (const float*)d_in[3];
    const float* be1 = (const float*)d_in[4];
    const float* w2  = (const float*)d_in[5];
    const float* b2  = (const float*)d_in[6];
    const float* g2  = (const float*)d_in[7];
    const float* be2 = (const float*)d_in[8];
    const float* fcw = (const float*)d_in[9];
    const float* fcb = (const float*)d_in[10];
    float* out = (float*)d_out;
    int B = in_sizes[0];
    float invB = 1.0f / (float)B;

    float* ws = (float*)d_ws;
    float* p1 = ws;          // 64*32 partials for BN1
    float* p2 = ws + 2048;   // 64*2 partials for BN2
    float* cf = ws + 2176;   // folded BN1+Linear2 coef [17]
    unsigned int* ctr = (unsigned int*)(ws + 2240);  // barrier ctr (reset/launch)

    // Reset barrier counter every launch (graph-legal async memset node):
    // every capture/replay runs the identical deterministic sequence.
    hipMemsetAsync(ctr, 0, sizeof(unsigned int), stream);

    k_stats<<<64, 256, 0, stream>>>(x, w1, b1, w2, b2, g1, be1,
                                    p1, p2, cf, ctr, B, invB);

    const int blocks = 1024;                // 4 blocks/CU, single dispatch round
    const int nw = blocks * 4;              // 4096 waves, 1 row each per sweep
    int iters = (B + nw - 1) / nw;          // 8 sweeps for B=32768
    k_tree<<<blocks, 256, 0, stream>>>(x, w1, b1, g2, be2, fcw, fcb, p2, cf,
                                       out, B, invB, iters, nw);
}

// Round 15
// 56.821 us; speedup vs baseline: 1.2365x; 1.2365x over previous
//
#include <hip/hip_runtime.h>

#define LEAKY_S 0.01f
#define BN_EPS 1e-5f
#define LOG2E 1.44269504088896340736f

typedef float f32x2 __attribute__((ext_vector_type(2)));
typedef float f32x4 __attribute__((ext_vector_type(4)));

__device__ __forceinline__ float leaky(float v) { return v >= 0.0f ? v : LEAKY_S * v; }
__device__ __forceinline__ float fast_exp2(float v) { return __builtin_amdgcn_exp2f(v); }
// sigmoid(z) with weights pre-scaled by log2e
__device__ __forceinline__ float sig2(float z2) {
    return __builtin_amdgcn_rcpf(1.0f + fast_exp2(-z2));
}
__device__ __forceinline__ void st4(float* p, float a, float b, float c, float d) {
    f32x4 v = {a, b, c, d}; *(f32x4*)p = v;   // cached store (R7 winner)
}

// ---------------- K1: partial sums (sum, sumsq) of h1 columns over batch ----
__global__ __launch_bounds__(256) void k_part1(const float* __restrict__ x,
        const float* __restrict__ w1, const float* __restrict__ b1,
        float* __restrict__ p1, int B) {
    float w1r[16], b1r[16], s[16], q[16];
#pragma unroll
    for (int j = 0; j < 16; ++j) { w1r[j] = w1[j]; b1r[j] = b1[j]; s[j] = 0.f; q[j] = 0.f; }
    int tid = threadIdx.x;
    int i = blockIdx.x * 256 + tid;
    if (2 * i < B) {
        f32x2 xv = *(const f32x2*)(x + 2 * i);
#pragma unroll
        for (int e = 0; e < 2; ++e) {
#pragma unroll
            for (int j = 0; j < 16; ++j) {
                float h = leaky(fmaf(xv[e], w1r[j], b1r[j]));
                s[j] += h; q[j] += h * h;
            }
        }
    }
#pragma unroll
    for (int j = 0; j < 16; ++j) {
        for (int off = 32; off >= 1; off >>= 1) {
            s[j] += __shfl_xor(s[j], off, 64);
            q[j] += __shfl_xor(q[j], off, 64);
        }
    }
    __shared__ float red[4][32];
    int w = tid >> 6, lane = tid & 63;
    if (lane == 0) {
#pragma unroll
        for (int j = 0; j < 16; ++j) { red[w][j] = s[j]; red[w][j + 16] = q[j]; }
    }
    __syncthreads();
    if (tid < 32)
        p1[blockIdx.x * 32 + tid] = red[0][tid] + red[1][tid] + red[2][tid] + red[3][tid];
}

// Wave0 helper: fold BN1 + Linear2 into coef[0..15]=a[j], coef[16]=c0.
__device__ __forceinline__ void fold_bn1(const float* __restrict__ p1,
        const float* __restrict__ w2, const float* __restrict__ b2,
        const float* __restrict__ g1, const float* __restrict__ be1,
        float* coef, int tid, float invB) {
    float acc = 0.f;
    for (int i = 0; i < 64; ++i) acc += p1[i * 32 + tid];
    float qacc = __shfl(acc, tid + 16, 64);   // lanes 0..15 fetch sumsq
    float cp = 0.f;
    if (tid < 16) {
        float mean = acc * invB;
        float var  = qacc * invB - mean * mean;
        float inv  = rsqrtf(var + BN_EPS) * g1[tid];
        float sh   = fmaf(-mean, inv, be1[tid]);
        coef[tid] = inv * w2[tid];
        cp = sh * w2[tid];
    }
    for (int off = 8; off >= 1; off >>= 1) cp += __shfl_xor(cp, off, 16);
    if (tid == 0) coef[16] = cp + b2[0];
}

// -------- K2: fold BN1 (block0 publishes coef to ws) + h2 stats partials ---
__global__ __launch_bounds__(256) void k_h2f(const float* __restrict__ x,
        const float* __restrict__ w1, const float* __restrict__ b1,
        const float* __restrict__ p1, const float* __restrict__ w2,
        const float* __restrict__ b2, const float* __restrict__ g1,
        const float* __restrict__ be1, float* __restrict__ p2,
        float* __restrict__ cfws, int B, float invB) {
    __shared__ float coef[17];
    int tid = threadIdx.x;
    if (tid < 32) fold_bn1(p1, w2, b2, g1, be1, coef, tid, invB);
    __syncthreads();
    if (blockIdx.x == 0 && tid < 17) cfws[tid] = coef[tid];
    float w1r[16], b1r[16], ar[16];
#pragma unroll
    for (int j = 0; j < 16; ++j) { w1r[j] = w1[j]; b1r[j] = b1[j]; ar[j] = coef[j]; }
    float c0 = coef[16];
    float s = 0.f, q = 0.f;
    int i = blockIdx.x * 256 + tid;
    if (2 * i < B) {
        f32x2 xv = *(const f32x2*)(x + 2 * i);
#pragma unroll
        for (int e = 0; e < 2; ++e) {
            float acc = c0;
#pragma unroll
            for (int j = 0; j < 16; ++j) {
                float h = leaky(fmaf(xv[e], w1r[j], b1r[j]));
                acc = fmaf(h, ar[j], acc);
            }
            float h2 = leaky(acc);
            s += h2; q += h2 * h2;
        }
    }
    for (int off = 32; off >= 1; off >>= 1) {
        s += __shfl_xor(s, off, 64);
        q += __shfl_xor(q, off, 64);
    }
    __shared__ float red[4][2];
    int w = tid >> 6, lane = tid & 63;
    if (lane == 0) { red[w][0] = s; red[w][1] = q; }
    __syncthreads();
    if (tid == 0) {
        p2[blockIdx.x * 2 + 0] = red[0][0] + red[1][0] + red[2][0] + red[3][0];
        p2[blockIdx.x * 2 + 1] = red[0][1] + red[1][1] + red[2][1] + red[3][1];
    }
}

// ---------------- K3: register tree, 4 rows per wave (loop), 16 rows/block -
// Prologue (weight stage + BN2 fold) amortized over 4 row-iterations; the
// per-row body is the register tree with the cached dwordx4 burst.
__global__ __launch_bounds__(256, 4) void k_tree(const float* __restrict__ x,
        const float* __restrict__ w1, const float* __restrict__ b1,
        const float* __restrict__ g2, const float* __restrict__ be2,
        const float* __restrict__ fcw, const float* __restrict__ fcb,
        const float* __restrict__ p2, const float* __restrict__ cfws,
        float* __restrict__ out, int B, float invB) {
    __shared__ float wl[1024], bl[1024];
    __shared__ float x2s[16];      // h2 per block-row
    __shared__ float bn2[2];       // s2, t2
    int tid = threadIdx.x;

    // Stage fc weights raw, swizzled slot-major (same map as R3).
    for (int i = tid; i < 1024; i += 256) {
        int d;
        if (i < 128)      d = i;
        else if (i < 256) { int o = i - 128; d = 128 + ((o & 1) << 6) + (o >> 1); }
        else if (i < 512) { int o = i - 256; d = 256 + ((((o >> 7) << 1) | (o & 1)) << 6) + ((o & 127) >> 1); }
        else              { int o = i - 512; d = 512 + ((((o >> 7) << 1) | (o & 1)) << 6) + ((o & 127) >> 1); }
        wl[d] = fcw[i];
        bl[d] = fcb[i];
    }
    // Wave0: parallel BN2 stats reduce (64 partial pairs)
    if (tid < 64) {
        float s = p2[2 * tid], q = p2[2 * tid + 1];
        for (int off = 32; off >= 1; off >>= 1) {
            s += __shfl_xor(s, off, 64);
            q += __shfl_xor(q, off, 64);
        }
        if (tid == 0) {
            float mean = s * invB, var = q * invB - mean * mean;
            float inv = rsqrtf(var + BN_EPS) * g2[0];
            bn2[0] = inv;
            bn2[1] = fmaf(-mean, inv, be2[0]);
        }
    }
    // Wave1 lanes 0..15: h2 for this block's 16 rows (pre-BN2; BN2 in weights)
    if (tid >= 64 && tid < 80) {
        int rr = tid - 64;
        int r = blockIdx.x * 16 + rr;
        float xv = (r < B) ? x[r] : 0.f;
        float acc = cfws[16];
#pragma unroll
        for (int j = 0; j < 16; ++j) {
            float h = leaky(fmaf(xv, w1[j], b1[j]));
            acc = fmaf(h, cfws[j], acc);
        }
        x2s[rr] = leaky(acc);
    }
    __syncthreads();
    // Fold BN2 into weights: z*log2e = h2*(s2*w*log2e) + (t2*w + b)*log2e
    {
        float s2k = bn2[0] * LOG2E, t2 = bn2[1];
        for (int i = tid; i < 1024; i += 256) {
            float wv = wl[i];
            wl[i] = wv * s2k;
            bl[i] = fmaf(t2, wv, bl[i]) * LOG2E;
        }
    }
    __syncthreads();

    const int w = tid >> 6, lane = tid & 63;
#pragma unroll 1
    for (int it = 0; it < 4; ++it) {
        const int r = blockIdx.x * 16 + w * 4 + it;
        const bool act = r < B;              // wave-uniform
        const float x2 = x2s[w * 4 + it];
        float* op = out + (size_t)r * 2048;

        float s0q[4];                        // segment 0: floats 4*lane .. +3
        float mup;
        // ---- level 1 (uniform across lanes; no shuffle needed) ----
        {
            float z = fmaf(x2, wl[1], bl[1]);
            float pz = sig2(z);
            float c0 = pz, c1 = 1.0f - pz;   // mu parent = 1
            if (lane == 0) { s0q[0] = 0.f; s0q[1] = 1.f; s0q[2] = c0; s0q[3] = c1; }
            mup = (lane & 1) ? c1 : c0;
        }
        // ---- levels 2..6: shuffle levels; gather children into seg0 ----
#pragma unroll
        for (int l = 2; l <= 6; ++l) {
            const int P = 1 << (l - 1);
            float wv = wl[P + lane], bv = bl[P + lane];
            float z = fmaf(x2, wv, bv);
            float pz = sig2(z);
            float c0 = mup * pz, c1 = mup - c0;     // valid in lanes < P
            int sk = (2 * lane - P) & 63;
            float g0 = __shfl(c0, sk, 64);
            float g1 = __shfl(c1, sk, 64);
            float g2 = __shfl(c0, sk + 1, 64);
            float g3 = __shfl(c1, sk + 1, 64);
            if (lane >= P / 2 && lane < P) { s0q[0] = g0; s0q[1] = g1; s0q[2] = g2; s0q[3] = g3; }
            float n0 = __shfl(c0, lane >> 1, 64);
            float n1 = __shfl(c1, lane >> 1, 64);
            mup = (lane & 1) ? n1 : n0;
        }
        // ---- level 7: parent 64+lane; children stay in-lane + gather seg0 ----
        float c2v[2];
        {
            float wv = wl[64 + lane], bv = bl[64 + lane];
            float z = fmaf(x2, wv, bv);
            float pz = sig2(z);
            c2v[0] = mup * pz;
            c2v[1] = mup - c2v[0];
            int sk = (2 * lane - 64) & 63;
            float g0 = __shfl(c2v[0], sk, 64);
            float g1 = __shfl(c2v[1], sk, 64);
            float g2 = __shfl(c2v[0], sk + 1, 64);
            float g3 = __shfl(c2v[1], sk + 1, 64);
            if (lane >= 32) { s0q[0] = g0; s0q[1] = g1; s0q[2] = g2; s0q[3] = g3; }
        }
        // ---- level 8: parents {128+2i, 128+2i+1}; mus in-lane (c2v) ----
        float c4v[4];
#pragma unroll
        for (int s = 0; s < 2; ++s) {
            float wv = wl[128 + (s << 6) + lane], bv = bl[128 + (s << 6) + lane];
            float z = fmaf(x2, wv, bv);
            float pz = sig2(z);
            c4v[2 * s]     = c2v[s] * pz;
            c4v[2 * s + 1] = c2v[s] - c4v[2 * s];
        }
        // ---- level 9: parents {256 + j2*128 + 2i + s} ----
        float c8v[2][4];
#pragma unroll
        for (int j2 = 0; j2 < 2; ++j2) {
            int src = (j2 << 5) + (lane >> 1);
            float A  = __shfl(c4v[0], src, 64);
            float Bv = __shfl(c4v[1], src, 64);
            float C  = __shfl(c4v[2], src, 64);
            float D  = __shfl(c4v[3], src, 64);
            float m0 = (lane & 1) ? C : A;
            float m1 = (lane & 1) ? D : Bv;
            float wv0 = wl[256 + ((2 * j2) << 6) + lane],     bv0 = bl[256 + ((2 * j2) << 6) + lane];
            float wv1 = wl[256 + ((2 * j2 + 1) << 6) + lane], bv1 = bl[256 + ((2 * j2 + 1) << 6) + lane];
            float z0 = fmaf(x2, wv0, bv0);
            float z1 = fmaf(x2, wv1, bv1);
            float p0 = sig2(z0), p1v = sig2(z1);
            c8v[j2][0] = m0 * p0;
            c8v[j2][1] = m0 - c8v[j2][0];
            c8v[j2][2] = m1 * p1v;
            c8v[j2][3] = m1 - c8v[j2][2];
        }
        // ---- level 10: parents {512 + j*128 + 2i + s} ----
        float l10[4][4];
#pragma unroll
        for (int j = 0; j < 4; ++j) {
            const int j2 = j >> 1;
            int src = ((j & 1) << 5) + (lane >> 1);
            float A  = __shfl(c8v[j2][0], src, 64);
            float Bv = __shfl(c8v[j2][1], src, 64);
            float C  = __shfl(c8v[j2][2], src, 64);
            float D  = __shfl(c8v[j2][3], src, 64);
            float m0 = (lane & 1) ? C : A;
            float m1 = (lane & 1) ? D : Bv;
            float wv0 = wl[512 + ((2 * j) << 6) + lane],     bv0 = bl[512 + ((2 * j) << 6) + lane];
            float wv1 = wl[512 + ((2 * j + 1) << 6) + lane], bv1 = bl[512 + ((2 * j + 1) << 6) + lane];
            float z0 = fmaf(x2, wv0, bv0);
            float z1 = fmaf(x2, wv1, bv1);
            float p0 = sig2(z0), p1v = sig2(z1);
            l10[j][0] = m0 * p0;
            l10[j][1] = m0 - l10[j][0];
            l10[j][2] = m1 * p1v;
            l10[j][3] = m1 - l10[j][2];
        }
        // ---- burst: 8 back-to-back lane-contiguous dwordx4 cached stores ----
        if (act) {
            const int o4 = lane << 2;
            st4(op + o4,        s0q[0],    s0q[1],    s0q[2],    s0q[3]);
            st4(op + 256 + o4,  c4v[0],    c4v[1],    c4v[2],    c4v[3]);
            st4(op + 512 + o4,  c8v[0][0], c8v[0][1], c8v[0][2], c8v[0][3]);
            st4(op + 768 + o4,  c8v[1][0], c8v[1][1], c8v[1][2], c8v[1][3]);
            st4(op + 1024 + o4, l10[0][0], l10[0][1], l10[0][2], l10[0][3]);
            st4(op + 1280 + o4, l10[1][0], l10[1][1], l10[1][2], l10[1][3]);
            st4(op + 1536 + o4, l10[2][0], l10[2][1], l10[2][2], l10[2][3]);
            st4(op + 1792 + o4, l10[3][0], l10[3][1], l10[3][2], l10[3][3]);
        }
    }
}

extern "C" void kernel_launch(void* const* d_in, const int* in_sizes, int n_in,
                              void* d_out, int out_size, void* d_ws, size_t ws_size,
                              hipStream_t stream) {
    const float* x   = (const float*)d_in[0];
    const float* w1  = (const float*)d_in[1];
    const float* b1  = (const float*)d_in[2];
    const float* g1  = (const float*)d_in[3];
    const float* be1 = (const float*)d_in[4];
    const float* w2  = (const float*)d_in[5];
    const float* b2  = (const float*)d_in[6];
    const float* g2  = (const float*)d_in[7];
    const float* be2 = (const float*)d_in[8];
    const float* fcw = (const float*)d_in[9];
    const float* fcb = (const float*)d_in[10];
    float* out = (float*)d_out;
    int B = in_sizes[0];
    float invB = 1.0f / (float)B;

    float* ws = (float*)d_ws;
    float* p1 = ws;          // 64*32 partials for BN1
    float* p2 = ws + 2048;   // 64*2 partials for BN2
    float* cf = ws + 2176;   // folded BN1+Linear2 coef [17]

    k_part1<<<64, 256, 0, stream>>>(x, w1, b1, p1, B);
    k_h2f  <<<64, 256, 0, stream>>>(x, w1, b1, p1, w2, b2, g1, be1, p2, cf, B, invB);

    int blocks = (B + 15) / 16;   // 16 rows per block, 4 rows per wave (loop)
    k_tree<<<blocks, 256, 0, stream>>>(x, w1, b1, g2, be2, fcw, fcb, p2, cf,
                                       out, B, invB);
}